// Round 7
// baseline (1078.103 us; speedup 1.0000x reference)
//
#include <hip/hip_runtime.h>

// GTA model: GCN(2-hop) -> 3x transformer encoder -> 10-step AR predictor.
// R6: attention reads MFMA A-fragments directly from global (L2) -- no LDS
// staging, no K-loop barriers, whole grid co-resident. k_mu parallelized 16x.
// Predictor scan composed into a single 100x100 linear map (no nonlinearity).
// scores = x(0.1*WqWk^T)x^T ; out@wm = (attn@x)@(Wv@wm_h). W@Ust fused w/ LN.

#define ROWS 24576   // C*T = 32*768

// workspace offsets (floats)
#define OFF_ADJ   0L
#define OFF_X0    1024L
#define OFF_X1    (OFF_X0 + 2457600L)
#define OFF_HID   (OFF_X1 + 2457600L)
#define OFF_XROW  (OFF_HID + 1474560L)       // 24576*128 bf16 = 1572864 floats
#define OFF_XT    (OFF_XROW + 1572864L)
#define OFF_WBF   (OFF_XT + 1572864L)        // 24576*512 bf16 = 6291456 floats
#define OFF_MHT   (OFF_WBF + 6291456L)       // 15*128*128 bf16 = 122880 floats
#define OFF_USTT  (OFF_MHT + 122880L)        // 3*128*512 bf16 = 98304 floats
#define OFF_MP    (OFF_USTT + 98304L)        // 100*100 fp32
#define OFF_C0    (OFF_MP + 10000L)          // 100 fp32

typedef __attribute__((ext_vector_type(8))) short short8;
typedef __attribute__((ext_vector_type(4))) float float4v;
typedef __attribute__((ext_vector_type(2))) unsigned int uint2v;

__device__ inline unsigned short f2bf(float f) {
    unsigned u = __builtin_bit_cast(unsigned, f);
    return (unsigned short)((u + 0x7fffu + ((u >> 16) & 1u)) >> 16);
}
__device__ inline unsigned pk2bf(float lo, float hi) {
    return (unsigned)f2bf(lo) | ((unsigned)f2bf(hi) << 16);
}

// ---------------- adjacency normalization ----------------
__global__ void __launch_bounds__(1024) k_adj(const float* __restrict__ A, float* __restrict__ adjh) {
    __shared__ float adj[32][32];
    __shared__ float rs[32];
    int tid = threadIdx.x;
    int i = tid >> 5, j = tid & 31;
    float v = A[i*32 + j] + (i == j ? 1.f : 0.f);
    adj[i][j] = v;
    __syncthreads();
    if (tid < 32) {
        float s = 0.f;
        #pragma unroll
        for (int jj = 0; jj < 32; ++jj) s += adj[tid][jj];
        rs[tid] = s;
    }
    __syncthreads();
    adjh[i*32 + j] = adj[i][j] / rs[i];
}

// ---------------- precompute (parallel): MhT, UstT (bf16, padded), Mpred=w1@w2, c0=b1@w2+b2 ----
// blocks 0..479: 30 matmuls x 16 subtiles of 625 outputs. 480..495: Mpred. 496: c0.
__global__ void __launch_bounds__(256) k_mu2(const float* __restrict__ wq, const float* __restrict__ wk,
                                             const float* __restrict__ wv, const float* __restrict__ wm,
                                             const float* __restrict__ l1w, const float* __restrict__ l1b,
                                             const float* __restrict__ l2w, const float* __restrict__ l2b,
                                             unsigned short* __restrict__ MhT, unsigned short* __restrict__ UstT,
                                             float* __restrict__ Mp, float* __restrict__ c0v) {
    int bi = blockIdx.x, tid = threadIdx.x;
    if (bi < 480) {
        int mat = bi >> 4, sub = bi & 15;
        int mode = mat / 15, idx = mat % 15, l = idx / 5, h = idx % 5;
        const float* Asrc = (mode == 0 ? wq : wv) + (l*5 + h)*10000;
        const float* Bsrc = (mode == 0) ? (wk + (l*5 + h)*10000) : (wm + l*50000 + h*10000);
        int oend = sub*625 + 625;
        for (int o = sub*625 + tid; o < oend; o += 256) {
            int r = o / 100, cix = o - (o/100)*100;
            const float* arow = Asrc + r*100;
            float acc = 0.f;
            if (mode == 0) {
                const float* brow = Bsrc + cix*100;
                for (int e = 0; e < 100; ++e) acc += arow[e] * brow[e];
                MhT[(long)(l*5 + h)*16384 + cix*128 + r] = f2bf(acc * 0.1f);
            } else {
                for (int e = 0; e < 100; ++e) acc += arow[e] * Bsrc[e*100 + cix];
                UstT[(long)l*65536 + (long)cix*512 + h*100 + r] = f2bf(acc);
            }
        }
        if (sub == 0) {   // zero padding
            if (mode == 0) {
                unsigned short* M0 = MhT + (long)(l*5 + h)*16384;
                for (int i = tid; i < 28*128; i += 256) M0[(100 + i/128)*128 + (i%128)] = 0;
                for (int i = tid; i < 100*28; i += 256) M0[(i/28)*128 + 100 + (i%28)] = 0;
            } else if (h == 4) {
                unsigned short* U0 = UstT + (long)l*65536;
                for (int i = tid; i < 28*512; i += 256) U0[(long)(100 + i/512)*512 + (i%512)] = 0;
                for (int i = tid; i < 100*12; i += 256) U0[(long)(i/12)*512 + 500 + (i%12)] = 0;
            }
        }
    } else if (bi < 496) {
        int sub = bi - 480;
        int oend = sub*625 + 625;
        for (int o = sub*625 + tid; o < oend; o += 256) {
            int r = o / 100, cix = o - (o/100)*100;
            const float* arow = l1w + r*200;
            float acc = 0.f;
            for (int e = 0; e < 200; ++e) acc += arow[e] * l2w[e*100 + cix];
            Mp[r*100 + cix] = acc;
        }
    } else {
        if (tid < 100) {
            float acc = l2b[tid];
            for (int e = 0; e < 200; ++e) acc += l1b[e] * l2w[e*100 + tid];
            c0v[tid] = acc;
        }
    }
}

// ---------------- spmm: Y[i,f] = sum_j adjh[i,j] * Xin[j,f] ----------------
__global__ void __launch_bounds__(256) k_spmm(const float* __restrict__ adjh, const float* __restrict__ Xin,
                                              float* __restrict__ Y, int F) {
    __shared__ float adj[1024];
    int tid = threadIdx.x;
    for (int i = tid; i < 1024; i += 256) adj[i] = adjh[i];
    __syncthreads();
    long f = (long)blockIdx.x * 256 + tid;
    float acc[32];
    #pragma unroll
    for (int i = 0; i < 32; ++i) acc[i] = 0.f;
    for (int jj = 0; jj < 32; ++jj) {
        float xv = Xin[jj*(long)F + f];
        #pragma unroll
        for (int i = 0; i < 32; ++i) acc[i] += adj[i*32 + jj] * xv;
    }
    #pragma unroll
    for (int i = 0; i < 32; ++i) Y[i*(long)F + f] = acc[i];
}

// ---------------- fp32 tiled GEMM (GCN only) ----------------
template<int NCOLS, bool RELU, bool BIAS>
__global__ void __launch_bounds__(256) k_gemm(const float* __restrict__ A, const float* __restrict__ B,
                                              const float* __restrict__ bias, float* __restrict__ Cc,
                                              int M, int N, int K) {
    constexpr int NP = 8*NCOLS;
    int tid = threadIdx.x;
    int m0 = blockIdx.x * 32;
    int mloc = tid & 31, grp = tid >> 5;
    int n0 = grp * NCOLS;
    __shared__ float As[32][33];
    __shared__ float Bs[32][NP + 1];
    float acc[NCOLS];
    #pragma unroll
    for (int i2 = 0; i2 < NCOLS; ++i2) acc[i2] = 0.f;
    for (int k0 = 0; k0 < K; k0 += 32) {
        #pragma unroll
        for (int st = 0; st < 4; ++st) {
            int rr = (tid >> 5) + st*8, kk = tid & 31, gk = k0 + kk;
            As[rr][kk] = (gk < K) ? A[(long)(m0 + rr)*K + gk] : 0.f;
        }
        for (int i2 = tid; i2 < 32*NP; i2 += 256) {
            int kk = i2 / NP, nn = i2 - kk*NP;
            int gk = k0 + kk;
            Bs[kk][nn] = (gk < K && nn < N) ? B[(long)gk*N + nn] : 0.f;
        }
        __syncthreads();
        #pragma unroll 8
        for (int kk = 0; kk < 32; ++kk) {
            float a = As[mloc][kk];
            #pragma unroll
            for (int j2 = 0; j2 < NCOLS; ++j2) acc[j2] += a * Bs[kk][n0 + j2];
        }
        __syncthreads();
    }
    #pragma unroll
    for (int j2 = 0; j2 < NCOLS; ++j2) {
        int nn = n0 + j2;
        if (nn < N) {
            float v = acc[j2];
            if (BIAS) v += bias[nn];
            if (RELU) v = fmaxf(v, 0.f);
            Cc[(long)(m0 + mloc)*N + nn] = v;
        }
    }
}

// ---------------- x fp32 -> bf16 row-major [c][t][128] and transposed [c][128][t] ----------------
__global__ void __launch_bounds__(256) k_prep(const float* __restrict__ x, unsigned short* __restrict__ xrow,
                                              unsigned short* __restrict__ xT) {
    int c = blockIdx.y, t0 = blockIdx.x * 64;
    int tid = threadIdx.x;
    __shared__ float xs[64][101];
    const float* xp = x + ((long)c*768 + t0) * 100;
    for (int i = tid; i < 6400; i += 256) {
        int r = i / 100, d = i - r*100;
        xs[r][d] = xp[i];
    }
    __syncthreads();
    unsigned short* xro = xrow + ((long)c*768 + t0) * 128;
    for (int i = tid; i < 8192; i += 256) {
        int r = i >> 7, d = i & 127;
        xro[i] = (d < 100) ? f2bf(xs[r][d]) : (unsigned short)0;
    }
    unsigned short* xto = xT + (long)c*128*768 + t0;
    for (int i = tid; i < 8192; i += 256) {
        int d = i >> 6, t = i & 63;
        xto[(long)d*768 + t] = (d < 100) ? f2bf(xs[t][d]) : (unsigned short)0;
    }
}

// ---------------- fused Q-proj + flash attention, direct-global A-fragments ----------------
// grid (6, 5, 32) = (128-query tile, h, c); block 256 = 4 waves x 16 queries x 2 subtiles.
// S^T = x_k.Q^T with A-frags straight from xrow; O^T = x^T.P^T with A-frags straight
// from xT. Only wave-private P scratch lives in LDS -> no K-loop barriers at all.
#define QP_STRIDE 136
#define PT_STRIDE 72

__global__ void __launch_bounds__(256) k_attn5(const unsigned short* __restrict__ xrow,
                                               const unsigned short* __restrict__ xT,
                                               const unsigned short* __restrict__ MhT,
                                               unsigned short* __restrict__ Wb) {
    __shared__ __align__(16) short scratch[4][2304];        // 18432 B total
    const int tid = threadIdx.x;
    const int wave = tid >> 6, lane = tid & 63;
    const int l15 = lane & 15, l4 = lane >> 4;
    const int c = blockIdx.z, h = blockIdx.y, q0 = blockIdx.x * 128;
    short* myq = scratch[wave];
    short* pt0 = scratch[wave];
    short* pt1 = scratch[wave] + 1152;

    // ---- Q^T = MhT . x^T : both operands direct from global ----
    short8 qb0[4], qb1[4];
    {
        const short* xq = (const short*)xrow + ((long)c*768 + q0 + wave*16 + l15)*128 + l4*8;
        short8 bq0[4], bq1[4];
        #pragma unroll
        for (int kk = 0; kk < 4; ++kk) {
            bq0[kk] = *(const short8*)(xq + kk*32);
            bq1[kk] = *(const short8*)(xq + 64*128 + kk*32);
        }
        const short* Mb = (const short*)MhT + (long)h*16384 + l15*128 + l4*8;
        float4v qc0[8], qc1[8];
        #pragma unroll
        for (int mt = 0; mt < 8; ++mt) { qc0[mt] = (float4v){0,0,0,0}; qc1[mt] = (float4v){0,0,0,0}; }
        #pragma unroll
        for (int mt = 0; mt < 8; ++mt) {
            #pragma unroll
            for (int kk = 0; kk < 4; ++kk) {
                short8 a = *(const short8*)(Mb + (mt*16)*128 + kk*32);
                qc0[mt] = __builtin_amdgcn_mfma_f32_16x16x32_bf16(a, bq0[kk], qc0[mt], 0, 0, 0);
                qc1[mt] = __builtin_amdgcn_mfma_f32_16x16x32_bf16(a, bq1[kk], qc1[mt], 0, 0, 0);
            }
        }
        // C-layout (d=mt*16+l4*4+r, q=l15) -> row-major Q[q][d] via packed b64 (same lane)
        #pragma unroll
        for (int mt = 0; mt < 8; ++mt)
            *(uint2v*)(myq + l15*QP_STRIDE + mt*16 + l4*4) =
                (uint2v){pk2bf(qc0[mt][0], qc0[mt][1]), pk2bf(qc0[mt][2], qc0[mt][3])};
        #pragma unroll
        for (int kk = 0; kk < 4; ++kk) qb0[kk] = *(const short8*)(myq + l15*QP_STRIDE + kk*32 + l4*8);
        #pragma unroll
        for (int mt = 0; mt < 8; ++mt)
            *(uint2v*)(myq + l15*QP_STRIDE + mt*16 + l4*4) =
                (uint2v){pk2bf(qc1[mt][0], qc1[mt][1]), pk2bf(qc1[mt][2], qc1[mt][3])};
        #pragma unroll
        for (int kk = 0; kk < 4; ++kk) qb1[kk] = *(const short8*)(myq + l15*QP_STRIDE + kk*32 + l4*8);
    }

    float4v o0[7], o1[7];
    #pragma unroll
    for (int n = 0; n < 7; ++n) { o0[n] = (float4v){0,0,0,0}; o1[n] = (float4v){0,0,0,0}; }
    float lsum0 = 0.f, lsum1 = 0.f;

    const short* xrg = (const short*)xrow + (long)c*768*128;
    const short* xtg = (const short*)xT + (long)c*128*768;

    for (int kt = 0; kt < 12; ++kt) {
        const int key0 = kt * 64;

        // S^T: A-frags direct from xrow (16B aligned, 64B segments per 4 lanes)
        float4v s0[4], s1[4];
        #pragma unroll
        for (int kn = 0; kn < 4; ++kn) { s0[kn] = (float4v){0,0,0,0}; s1[kn] = (float4v){0,0,0,0}; }
        #pragma unroll
        for (int kn = 0; kn < 4; ++kn) {
            const short* ar = xrg + (long)(key0 + kn*16 + l15)*128 + l4*8;
            #pragma unroll
            for (int kk = 0; kk < 4; ++kk) {
                short8 a = *(const short8*)(ar + kk*32);
                s0[kn] = __builtin_amdgcn_mfma_f32_16x16x32_bf16(a, qb0[kk], s0[kn], 0, 0, 0);
                s1[kn] = __builtin_amdgcn_mfma_f32_16x16x32_bf16(a, qb1[kk], s1[kn], 0, 0, 0);
            }
        }

        // p = exp(s); same-lane pack (keys in the register index) -> b64 LDS writes
        #pragma unroll
        for (int kn = 0; kn < 4; ++kn) {
            float p0[4], p1[4];
            #pragma unroll
            for (int r = 0; r < 4; ++r) {
                p0[r] = __expf(s0[kn][r]); lsum0 += p0[r];
                p1[r] = __expf(s1[kn][r]); lsum1 += p1[r];
            }
            *(uint2v*)(pt0 + l15*PT_STRIDE + kn*16 + l4*4) =
                (uint2v){pk2bf(p0[0], p0[1]), pk2bf(p0[2], p0[3])};
            *(uint2v*)(pt1 + l15*PT_STRIDE + kn*16 + l4*4) =
                (uint2v){pk2bf(p1[0], p1[1]), pk2bf(p1[2], p1[3])};
        }

        // O^T += x^T . P^T : A-frags direct from xT
        #pragma unroll
        for (int kk2 = 0; kk2 < 2; ++kk2) {
            short8 b0 = *(const short8*)(pt0 + l15*PT_STRIDE + kk2*32 + l4*8);
            short8 b1 = *(const short8*)(pt1 + l15*PT_STRIDE + kk2*32 + l4*8);
            #pragma unroll
            for (int dt = 0; dt < 7; ++dt) {
                short8 a = *(const short8*)(xtg + (long)(dt*16 + l15)*768 + key0 + kk2*32 + l4*8);
                o0[dt] = __builtin_amdgcn_mfma_f32_16x16x32_bf16(a, b0, o0[dt], 0, 0, 0);
                o1[dt] = __builtin_amdgcn_mfma_f32_16x16x32_bf16(a, b1, o1[dt], 0, 0, 0);
            }
        }
    }

    // final l reduction over l4 groups (query = l15)
    float l0 = lsum0, l1 = lsum1;
    l0 += __shfl_xor(l0, 16, 64); l0 += __shfl_xor(l0, 32, 64);
    l1 += __shfl_xor(l1, 16, 64); l1 += __shfl_xor(l1, 32, 64);
    float inv0 = 1.f / l0, inv1 = 1.f / l1;

    // O^T C-layout: (d = dt*16 + l4*4 + r, q = l15) -> packed b64 stores
    unsigned short* Wo0 = Wb + ((long)(c*768 + q0 + wave*16 + l15))*512 + h*100 + l4*4;
    unsigned short* Wo1 = Wo0 + 64*512;
    #pragma unroll
    for (int dt = 0; dt < 7; ++dt) {
        if (dt < 6 || l4 == 0) {
            *(uint2v*)(Wo0 + dt*16) = (uint2v){pk2bf(o0[dt][0]*inv0, o0[dt][1]*inv0),
                                               pk2bf(o0[dt][2]*inv0, o0[dt][3]*inv0)};
            *(uint2v*)(Wo1 + dt*16) = (uint2v){pk2bf(o1[dt][0]*inv1, o1[dt][1]*inv1),
                                               pk2bf(o1[dt][2]*inv1, o1[dt][3]*inv1)};
        }
    }
    if (h == 0) {
        unsigned short* Wz = Wb + ((long)c*768 + q0)*512 + 500;
        for (int i = tid; i < 1536; i += 256) Wz[(long)(i/12)*512 + (i%12)] = 0;
    }
}

// ---------------- MFMA W@UstT + residual + LayerNorm ----------------
__global__ void __launch_bounds__(256) k_wmln(const unsigned short* __restrict__ Wb,
                                              const unsigned short* __restrict__ UstT,
                                              const float* __restrict__ x0,
                                              const float* __restrict__ g, const float* __restrict__ b,
                                              float* __restrict__ y) {
    const int tid = threadIdx.x, wave = tid >> 6, lane = tid & 63;
    const int l15 = lane & 15, l4 = lane >> 4;
    const long r0 = (long)blockIdx.x*64 + wave*16;
    const short* Ab = (const short*)Wb + (r0 + l15)*512 + l4*8;
    const short* Bb = (const short*)UstT;
    float4v o[8];
    #pragma unroll
    for (int n = 0; n < 8; ++n) o[n] = (float4v){0.f, 0.f, 0.f, 0.f};
    for (int ks = 0; ks < 16; ++ks) {
        short8 a = *(const short8*)(Ab + ks*32);
        #pragma unroll
        for (int n = 0; n < 8; ++n) {
            short8 bb = *(const short8*)(Bb + (long)(n*16 + l15)*512 + ks*32 + l4*8);
            o[n] = __builtin_amdgcn_mfma_f32_16x16x32_bf16(a, bb, o[n], 0, 0, 0);
        }
    }
    #pragma unroll
    for (int r = 0; r < 4; ++r) {
        long row = r0 + l4*4 + r;
        float sum = 0.f;
        #pragma unroll
        for (int n = 0; n < 8; ++n) {
            int col = n*16 + l15;
            float z = 0.f;
            if (col < 100) { z = o[n][r] + x0[row*100 + col]; sum += z; }
            o[n][r] = z;
        }
        #pragma unroll
        for (int off = 1; off < 16; off <<= 1) sum += __shfl_xor(sum, off, 64);
        float mean = sum * 0.01f;
        float vs = 0.f;
        #pragma unroll
        for (int n = 0; n < 8; ++n) {
            int col = n*16 + l15;
            if (col < 100) { float d = o[n][r] - mean; vs += d*d; }
        }
        #pragma unroll
        for (int off = 1; off < 16; off <<= 1) vs += __shfl_xor(vs, off, 64);
        float inv = rsqrtf(vs * 0.01f + 1e-5f);
        #pragma unroll
        for (int n = 0; n < 8; ++n) {
            int col = n*16 + l15;
            if (col < 100) y[row*100 + col] = (o[n][r] - mean) * inv * g[col] + b[col];
        }
    }
}

// ---------------- fused FFN + residual + LN ----------------
__global__ void __launch_bounds__(256) k_ffn(const float* __restrict__ x,
        const float* __restrict__ f1w, const float* __restrict__ f1b,
        const float* __restrict__ f2w, const float* __restrict__ f2b,
        const float* __restrict__ g, const float* __restrict__ b,
        float* __restrict__ y) {
    int tid = threadIdx.x, wid = tid >> 6, lane = tid & 63;
    long base = ((long)blockIdx.x*4 + wid) * 100;
    __shared__ float xs[4][100];
    __shared__ float ts[4][64];
    bool has2 = lane < 36;
    xs[wid][lane] = x[base + lane];
    if (has2) xs[wid][64 + lane] = x[base + 64 + lane];
    __syncthreads();
    float t = f1b[lane];
    for (int k = 0; k < 100; ++k) t += xs[wid][k] * f1w[k*64 + lane];
    ts[wid][lane] = fmaxf(t, 0.f);
    __syncthreads();
    float z0 = f2b[lane];
    float z1 = has2 ? f2b[64 + lane] : 0.f;
    for (int k = 0; k < 64; ++k) {
        float tv = ts[wid][k];
        z0 += tv * f2w[k*100 + lane];
        if (has2) z1 += tv * f2w[k*100 + 64 + lane];
    }
    z0 += xs[wid][lane];
    if (has2) z1 += xs[wid][64 + lane];
    float s = z0 + z1;
    #pragma unroll
    for (int off = 1; off < 64; off <<= 1) s += __shfl_xor(s, off, 64);
    float mean = s * 0.01f;
    float d0 = z0 - mean;
    float d1 = has2 ? (z1 - mean) : 0.f;
    float vs = d0*d0 + d1*d1;
    #pragma unroll
    for (int off = 1; off < 64; off <<= 1) vs += __shfl_xor(vs, off, 64);
    float inv = rsqrtf(vs * 0.01f + 1e-5f);
    y[base + lane] = d0 * inv * g[lane] + b[lane];
    if (has2) y[base + 64 + lane] = d1 * inv * g[64 + lane] + b[64 + lane];
}

// ---------------- autoregressive predictor (composed linear map) ----------------
__global__ void __launch_bounds__(256) k_pred2(const float* __restrict__ xf,
        const float* __restrict__ Mp, const float* __restrict__ c0v,
        float* __restrict__ out) {
    int c = blockIdx.x, tid = threadIdx.x;
    __shared__ float Ml[10000];
    __shared__ float carry[100];
    for (int i = tid; i < 10000; i += 256) Ml[i] = Mp[i];
    if (tid < 100) carry[tid] = xf[((long)c*768 + 767)*100 + tid];
    __syncthreads();
    for (int s = 0; s < 10; ++s) {
        float pv = 0.f;
        if (tid < 100) {
            pv = c0v[tid];
            for (int d = 0; d < 100; ++d) pv += carry[d] * Ml[d*100 + tid];
            out[((long)c*10 + s)*100 + tid] = pv;
        }
        __syncthreads();
        if (tid < 100) carry[tid] = pv;
        __syncthreads();
    }
}

extern "C" void kernel_launch(void* const* d_in, const int* in_sizes, int n_in,
                              void* d_out, int out_size, void* d_ws, size_t ws_size,
                              hipStream_t stream) {
    const float* X    = (const float*)d_in[0];
    const float* A    = (const float*)d_in[1];
    const float* gw1  = (const float*)d_in[2];
    const float* gb1  = (const float*)d_in[3];
    const float* gw2  = (const float*)d_in[4];
    const float* gb2  = (const float*)d_in[5];
    const float* wq   = (const float*)d_in[6];
    const float* wk   = (const float*)d_in[7];
    const float* wv   = (const float*)d_in[8];
    const float* wm   = (const float*)d_in[9];
    const float* f1w  = (const float*)d_in[10];
    const float* f1b  = (const float*)d_in[11];
    const float* f2w  = (const float*)d_in[12];
    const float* f2b  = (const float*)d_in[13];
    const float* ln1g = (const float*)d_in[14];
    const float* ln1b = (const float*)d_in[15];
    const float* ln2g = (const float*)d_in[16];
    const float* ln2b = (const float*)d_in[17];
    const float* l1w  = (const float*)d_in[18];
    const float* l1b  = (const float*)d_in[19];
    const float* l2w  = (const float*)d_in[20];
    const float* l2b  = (const float*)d_in[21];
    (void)in_sizes; (void)n_in; (void)out_size; (void)ws_size;

    float* ws   = (float*)d_ws;
    float* adjh = ws + OFF_ADJ;
    float* x0   = ws + OFF_X0;
    float* x1   = ws + OFF_X1;
    float* hid  = ws + OFF_HID;
    unsigned short* xrow = (unsigned short*)(ws + OFF_XROW);
    unsigned short* xTb  = (unsigned short*)(ws + OFF_XT);
    unsigned short* Wbf  = (unsigned short*)(ws + OFF_WBF);
    unsigned short* MhT  = (unsigned short*)(ws + OFF_MHT);
    unsigned short* UstT = (unsigned short*)(ws + OFF_USTT);
    float* Mp   = ws + OFF_MP;
    float* c0v  = ws + OFF_C0;
    float* out  = (float*)d_out;

    k_adj<<<1, 1024, 0, stream>>>(A, adjh);
    k_mu2<<<497, 256, 0, stream>>>(wq, wk, wv, wm, l1w, l1b, l2w, l2b, MhT, UstT, Mp, c0v);

    // GCN
    k_spmm<<<300, 256, 0, stream>>>(adjh, X, x1, 76800);
    k_gemm<8, true, true><<<768, 256, 0, stream>>>(x1, gw1, gb1, hid, ROWS, 60, 100);
    k_spmm<<<180, 256, 0, stream>>>(adjh, hid, x1, 46080);
    k_gemm<13, false, true><<<768, 256, 0, stream>>>(x1, gw2, gb2, x0, ROWS, 100, 60);

    // encoder layers
    for (int l = 0; l < 3; ++l) {
        k_prep<<<dim3(12,32), 256, 0, stream>>>(x0, xrow, xTb);
        k_attn5<<<dim3(6,5,32), 256, 0, stream>>>(xrow, xTb, MhT + (long)l*81920, Wbf);
        k_wmln<<<384, 256, 0, stream>>>(Wbf, UstT + (long)l*65536, x0,
                                        ln1g + l*100, ln1b + l*100, x1);
        k_ffn<<<6144, 256, 0, stream>>>(x1, f1w + l*6400, f1b + l*64, f2w + l*6400, f2b + l*100,
                                        ln2g + l*100, ln2b + l*100, x0);
    }

    k_pred2<<<32, 256, 0, stream>>>(x0, Mp, c0v, out);
}

// Round 8
// 767.474 us; speedup vs baseline: 1.4047x; 1.4047x over previous
//
#include <hip/hip_runtime.h>

// GTA model: GCN(2-hop) -> 3x transformer encoder -> 10-step AR predictor.
// R7: attention = R5 staged-LDS structure + global_load_lds(16B) DMA staging
// into XOR-swizzled unpadded tiles (conflict-free A-frag ds_read_b128).
// R6 lesson kept: direct-global A-frags are latency-bound; stage via LDS.
// scores = x(0.1*WqWk^T)x^T ; out@wm = (attn@x)@(Wv@wm_h). W@Ust fused w/ LN.

#define ROWS 24576   // C*T = 32*768

// workspace offsets (floats)
#define OFF_ADJ   0L
#define OFF_X0    1024L
#define OFF_X1    (OFF_X0 + 2457600L)
#define OFF_HID   (OFF_X1 + 2457600L)
#define OFF_XROW  (OFF_HID + 1474560L)       // 24576*128 bf16 = 1572864 floats
#define OFF_XT    (OFF_XROW + 1572864L)
#define OFF_WBF   (OFF_XT + 1572864L)        // 24576*512 bf16 = 6291456 floats
#define OFF_MHT   (OFF_WBF + 6291456L)       // 15*128*128 bf16 = 122880 floats
#define OFF_USTT  (OFF_MHT + 122880L)        // 3*128*512 bf16 = 98304 floats
#define OFF_MP    (OFF_USTT + 98304L)        // 100*100 fp32
#define OFF_C0    (OFF_MP + 10000L)          // 100 fp32

typedef __attribute__((ext_vector_type(8))) short short8;
typedef __attribute__((ext_vector_type(4))) float float4v;
typedef __attribute__((ext_vector_type(2))) unsigned int uint2v;

__device__ inline unsigned short f2bf(float f) {
    unsigned u = __builtin_bit_cast(unsigned, f);
    return (unsigned short)((u + 0x7fffu + ((u >> 16) & 1u)) >> 16);
}
__device__ inline unsigned pk2bf(float lo, float hi) {
    return (unsigned)f2bf(lo) | ((unsigned)f2bf(hi) << 16);
}
// async global->LDS DMA, 16B per lane; LDS dest = wave-uniform base + lane*16
__device__ inline void gload16(const short* g, short* l) {
    __builtin_amdgcn_global_load_lds((const __attribute__((address_space(1))) void*)g,
                                     (__attribute__((address_space(3))) void*)l, 16, 0, 0);
}

// ---------------- adjacency normalization ----------------
__global__ void __launch_bounds__(1024) k_adj(const float* __restrict__ A, float* __restrict__ adjh) {
    __shared__ float adj[32][32];
    __shared__ float rs[32];
    int tid = threadIdx.x;
    int i = tid >> 5, j = tid & 31;
    float v = A[i*32 + j] + (i == j ? 1.f : 0.f);
    adj[i][j] = v;
    __syncthreads();
    if (tid < 32) {
        float s = 0.f;
        #pragma unroll
        for (int jj = 0; jj < 32; ++jj) s += adj[tid][jj];
        rs[tid] = s;
    }
    __syncthreads();
    adjh[i*32 + j] = adj[i][j] / rs[i];
}

// ---------------- precompute (parallel): MhT, UstT (bf16, padded), Mpred=w1@w2, c0=b1@w2+b2 ----
__global__ void __launch_bounds__(256) k_mu2(const float* __restrict__ wq, const float* __restrict__ wk,
                                             const float* __restrict__ wv, const float* __restrict__ wm,
                                             const float* __restrict__ l1w, const float* __restrict__ l1b,
                                             const float* __restrict__ l2w, const float* __restrict__ l2b,
                                             unsigned short* __restrict__ MhT, unsigned short* __restrict__ UstT,
                                             float* __restrict__ Mp, float* __restrict__ c0v) {
    int bi = blockIdx.x, tid = threadIdx.x;
    if (bi < 480) {
        int mat = bi >> 4, sub = bi & 15;
        int mode = mat / 15, idx = mat % 15, l = idx / 5, h = idx % 5;
        const float* Asrc = (mode == 0 ? wq : wv) + (l*5 + h)*10000;
        const float* Bsrc = (mode == 0) ? (wk + (l*5 + h)*10000) : (wm + l*50000 + h*10000);
        int oend = sub*625 + 625;
        for (int o = sub*625 + tid; o < oend; o += 256) {
            int r = o / 100, cix = o - (o/100)*100;
            const float* arow = Asrc + r*100;
            float acc = 0.f;
            if (mode == 0) {
                const float* brow = Bsrc + cix*100;
                for (int e = 0; e < 100; ++e) acc += arow[e] * brow[e];
                MhT[(long)(l*5 + h)*16384 + cix*128 + r] = f2bf(acc * 0.1f);
            } else {
                for (int e = 0; e < 100; ++e) acc += arow[e] * Bsrc[e*100 + cix];
                UstT[(long)l*65536 + (long)cix*512 + h*100 + r] = f2bf(acc);
            }
        }
        if (sub == 0) {   // zero padding
            if (mode == 0) {
                unsigned short* M0 = MhT + (long)(l*5 + h)*16384;
                for (int i = tid; i < 28*128; i += 256) M0[(100 + i/128)*128 + (i%128)] = 0;
                for (int i = tid; i < 100*28; i += 256) M0[(i/28)*128 + 100 + (i%28)] = 0;
            } else if (h == 4) {
                unsigned short* U0 = UstT + (long)l*65536;
                for (int i = tid; i < 28*512; i += 256) U0[(long)(100 + i/512)*512 + (i%512)] = 0;
                for (int i = tid; i < 100*12; i += 256) U0[(long)(i/12)*512 + 500 + (i%12)] = 0;
            }
        }
    } else if (bi < 496) {
        int sub = bi - 480;
        int oend = sub*625 + 625;
        for (int o = sub*625 + tid; o < oend; o += 256) {
            int r = o / 100, cix = o - (o/100)*100;
            const float* arow = l1w + r*200;
            float acc = 0.f;
            for (int e = 0; e < 200; ++e) acc += arow[e] * l2w[e*100 + cix];
            Mp[r*100 + cix] = acc;
        }
    } else {
        if (tid < 100) {
            float acc = l2b[tid];
            for (int e = 0; e < 200; ++e) acc += l1b[e] * l2w[e*100 + tid];
            c0v[tid] = acc;
        }
    }
}

// ---------------- spmm: Y[i,f] = sum_j adjh[i,j] * Xin[j,f] ----------------
__global__ void __launch_bounds__(256) k_spmm(const float* __restrict__ adjh, const float* __restrict__ Xin,
                                              float* __restrict__ Y, int F) {
    __shared__ float adj[1024];
    int tid = threadIdx.x;
    for (int i = tid; i < 1024; i += 256) adj[i] = adjh[i];
    __syncthreads();
    long f = (long)blockIdx.x * 256 + tid;
    float acc[32];
    #pragma unroll
    for (int i = 0; i < 32; ++i) acc[i] = 0.f;
    for (int jj = 0; jj < 32; ++jj) {
        float xv = Xin[jj*(long)F + f];
        #pragma unroll
        for (int i = 0; i < 32; ++i) acc[i] += adj[i*32 + jj] * xv;
    }
    #pragma unroll
    for (int i = 0; i < 32; ++i) Y[i*(long)F + f] = acc[i];
}

// ---------------- fp32 tiled GEMM (GCN only) ----------------
template<int NCOLS, bool RELU, bool BIAS>
__global__ void __launch_bounds__(256) k_gemm(const float* __restrict__ A, const float* __restrict__ B,
                                              const float* __restrict__ bias, float* __restrict__ Cc,
                                              int M, int N, int K) {
    constexpr int NP = 8*NCOLS;
    int tid = threadIdx.x;
    int m0 = blockIdx.x * 32;
    int mloc = tid & 31, grp = tid >> 5;
    int n0 = grp * NCOLS;
    __shared__ float As[32][33];
    __shared__ float Bs[32][NP + 1];
    float acc[NCOLS];
    #pragma unroll
    for (int i2 = 0; i2 < NCOLS; ++i2) acc[i2] = 0.f;
    for (int k0 = 0; k0 < K; k0 += 32) {
        #pragma unroll
        for (int st = 0; st < 4; ++st) {
            int rr = (tid >> 5) + st*8, kk = tid & 31, gk = k0 + kk;
            As[rr][kk] = (gk < K) ? A[(long)(m0 + rr)*K + gk] : 0.f;
        }
        for (int i2 = tid; i2 < 32*NP; i2 += 256) {
            int kk = i2 / NP, nn = i2 - kk*NP;
            int gk = k0 + kk;
            Bs[kk][nn] = (gk < K && nn < N) ? B[(long)gk*N + nn] : 0.f;
        }
        __syncthreads();
        #pragma unroll 8
        for (int kk = 0; kk < 32; ++kk) {
            float a = As[mloc][kk];
            #pragma unroll
            for (int j2 = 0; j2 < NCOLS; ++j2) acc[j2] += a * Bs[kk][n0 + j2];
        }
        __syncthreads();
    }
    #pragma unroll
    for (int j2 = 0; j2 < NCOLS; ++j2) {
        int nn = n0 + j2;
        if (nn < N) {
            float v = acc[j2];
            if (BIAS) v += bias[nn];
            if (RELU) v = fmaxf(v, 0.f);
            Cc[(long)(m0 + mloc)*N + nn] = v;
        }
    }
}

// ---------------- x fp32 -> bf16 row-major [c][t][128] and transposed [c][128][t] ----------------
__global__ void __launch_bounds__(256) k_prep(const float* __restrict__ x, unsigned short* __restrict__ xrow,
                                              unsigned short* __restrict__ xT) {
    int c = blockIdx.y, t0 = blockIdx.x * 64;
    int tid = threadIdx.x;
    __shared__ float xs[64][101];
    const float* xp = x + ((long)c*768 + t0) * 100;
    for (int i = tid; i < 6400; i += 256) {
        int r = i / 100, d = i - r*100;
        xs[r][d] = xp[i];
    }
    __syncthreads();
    unsigned short* xro = xrow + ((long)c*768 + t0) * 128;
    for (int i = tid; i < 8192; i += 256) {
        int r = i >> 7, d = i & 127;
        xro[i] = (d < 100) ? f2bf(xs[r][d]) : (unsigned short)0;
    }
    unsigned short* xto = xT + (long)c*128*768 + t0;
    for (int i = tid; i < 8192; i += 256) {
        int d = i >> 6, t = i & 63;
        xto[(long)d*768 + t] = (d < 100) ? f2bf(xs[t][d]) : (unsigned short)0;
    }
}

// ---------------- fused Q-proj + flash attention, DMA-staged swizzled LDS ----------------
// grid (6, 5, 32) = (128-query tile, h, c); block 256 = 4 waves x 16 queries x 2 subtiles.
// xr tile: 64 keys x 128 d, rows 256B (16 chunks of 16B), chunk swizzle c^(row&7).
// xt tile: 112 d x 64 keys, rows 128B (8 chunks), same swizzle.
#define QP_STRIDE 136
#define PT_STRIDE 72

__global__ void __launch_bounds__(256) k_attn6(const unsigned short* __restrict__ xrow,
                                               const unsigned short* __restrict__ xT,
                                               const unsigned short* __restrict__ MhT,
                                               unsigned short* __restrict__ Wb) {
    __shared__ __align__(16) short xr[64 * 128];            // 16384 B
    __shared__ __align__(16) short xt[112 * 64];            // 14336 B
    __shared__ __align__(16) short scratch[4][2304];        // 18432 B: Q-xpose then pt0|pt1
    const int tid = threadIdx.x;
    const int wave = tid >> 6, lane = tid & 63;
    const int l15 = lane & 15, l4 = lane >> 4;
    const int c = blockIdx.z, h = blockIdx.y, q0 = blockIdx.x * 128;
    short* myq = scratch[wave];
    short* pt0 = scratch[wave];
    short* pt1 = scratch[wave] + 1152;

    // ---- Q^T = MhT . x^T : both operands direct from global (once per block) ----
    short8 qb0[4], qb1[4];
    {
        const short* xq = (const short*)xrow + ((long)c*768 + q0 + wave*16 + l15)*128 + l4*8;
        short8 bq0[4], bq1[4];
        #pragma unroll
        for (int kk = 0; kk < 4; ++kk) {
            bq0[kk] = *(const short8*)(xq + kk*32);
            bq1[kk] = *(const short8*)(xq + 64*128 + kk*32);
        }
        const short* Mb = (const short*)MhT + (long)h*16384 + l15*128 + l4*8;
        float4v qc0[8], qc1[8];
        #pragma unroll
        for (int mt = 0; mt < 8; ++mt) { qc0[mt] = (float4v){0,0,0,0}; qc1[mt] = (float4v){0,0,0,0}; }
        #pragma unroll
        for (int mt = 0; mt < 8; ++mt) {
            #pragma unroll
            for (int kk = 0; kk < 4; ++kk) {
                short8 a = *(const short8*)(Mb + (mt*16)*128 + kk*32);
                qc0[mt] = __builtin_amdgcn_mfma_f32_16x16x32_bf16(a, bq0[kk], qc0[mt], 0, 0, 0);
                qc1[mt] = __builtin_amdgcn_mfma_f32_16x16x32_bf16(a, bq1[kk], qc1[mt], 0, 0, 0);
            }
        }
        // C-layout (d=mt*16+l4*4+r, q=l15) -> row-major Q[q][d] via packed b64 (same lane)
        #pragma unroll
        for (int mt = 0; mt < 8; ++mt)
            *(uint2v*)(myq + l15*QP_STRIDE + mt*16 + l4*4) =
                (uint2v){pk2bf(qc0[mt][0], qc0[mt][1]), pk2bf(qc0[mt][2], qc0[mt][3])};
        #pragma unroll
        for (int kk = 0; kk < 4; ++kk) qb0[kk] = *(const short8*)(myq + l15*QP_STRIDE + kk*32 + l4*8);
        #pragma unroll
        for (int mt = 0; mt < 8; ++mt)
            *(uint2v*)(myq + l15*QP_STRIDE + mt*16 + l4*4) =
                (uint2v){pk2bf(qc1[mt][0], qc1[mt][1]), pk2bf(qc1[mt][2], qc1[mt][3])};
        #pragma unroll
        for (int kk = 0; kk < 4; ++kk) qb1[kk] = *(const short8*)(myq + l15*QP_STRIDE + kk*32 + l4*8);
    }

    float4v o0[7], o1[7];
    #pragma unroll
    for (int n = 0; n < 7; ++n) { o0[n] = (float4v){0,0,0,0}; o1[n] = (float4v){0,0,0,0}; }
    float lsum0 = 0.f, lsum1 = 0.f;

    const short* xrg = (const short*)xrow + (long)c*768*128;
    const short* xtg = (const short*)xT + (long)c*128*768;
    const int rl4 = lane >> 4, cp16 = lane & 15;   // xr DMA mapping
    const int rl8 = lane >> 3, cp8 = lane & 7;     // xt DMA mapping
    const int njt = (wave == 3) ? 2 : 4;           // xt rows: 112 = 3*32 + 16

    for (int kt = 0; kt < 12; ++kt) {
        const int key0 = kt * 64;
        // DMA stage: xr 64 rows x 256B (4 instrs/wave), xt 112 rows x 128B
        #pragma unroll
        for (int j = 0; j < 4; ++j) {
            int row = wave*16 + j*4 + rl4;
            int lc = cp16 ^ (row & 7);
            gload16(xrg + (long)(key0 + row)*128 + lc*8, xr + (wave*16 + j*4)*128);
        }
        for (int j = 0; j < njt; ++j) {
            int row = wave*32 + j*8 + rl8;
            int lc = cp8 ^ (row & 7);
            gload16(xtg + (long)row*768 + key0 + lc*8, xt + (wave*32 + j*8)*64);
        }
        __syncthreads();

        // S^T: rows=keys (4 tiles), cols=16 queries per subtile; swizzled A-frags
        float4v s0[4], s1[4];
        #pragma unroll
        for (int kn = 0; kn < 4; ++kn) { s0[kn] = (float4v){0,0,0,0}; s1[kn] = (float4v){0,0,0,0}; }
        #pragma unroll
        for (int kn = 0; kn < 4; ++kn) {
            #pragma unroll
            for (int kk = 0; kk < 4; ++kk) {
                short8 a = *(const short8*)(xr + (kn*16 + l15)*128 + (((kk*4 + l4) ^ (l15 & 7))*8));
                s0[kn] = __builtin_amdgcn_mfma_f32_16x16x32_bf16(a, qb0[kk], s0[kn], 0, 0, 0);
                s1[kn] = __builtin_amdgcn_mfma_f32_16x16x32_bf16(a, qb1[kk], s1[kn], 0, 0, 0);
            }
        }

        // p = exp(s); same-lane pack (keys in the register index) -> b64 LDS writes
        #pragma unroll
        for (int kn = 0; kn < 4; ++kn) {
            float p0[4], p1[4];
            #pragma unroll
            for (int r = 0; r < 4; ++r) {
                p0[r] = __expf(s0[kn][r]); lsum0 += p0[r];
                p1[r] = __expf(s1[kn][r]); lsum1 += p1[r];
            }
            *(uint2v*)(pt0 + l15*PT_STRIDE + kn*16 + l4*4) =
                (uint2v){pk2bf(p0[0], p0[1]), pk2bf(p0[2], p0[3])};
            *(uint2v*)(pt1 + l15*PT_STRIDE + kn*16 + l4*4) =
                (uint2v){pk2bf(p1[0], p1[1]), pk2bf(p1[2], p1[3])};
        }

        // O^T += x^T . P^T : swizzled xt A-frags
        #pragma unroll
        for (int kk2 = 0; kk2 < 2; ++kk2) {
            short8 b0 = *(const short8*)(pt0 + l15*PT_STRIDE + kk2*32 + l4*8);
            short8 b1 = *(const short8*)(pt1 + l15*PT_STRIDE + kk2*32 + l4*8);
            #pragma unroll
            for (int dt = 0; dt < 7; ++dt) {
                short8 a = *(const short8*)(xt + (dt*16 + l15)*64 + (((kk2*4 + l4) ^ (l15 & 7))*8));
                o0[dt] = __builtin_amdgcn_mfma_f32_16x16x32_bf16(a, b0, o0[dt], 0, 0, 0);
                o1[dt] = __builtin_amdgcn_mfma_f32_16x16x32_bf16(a, b1, o1[dt], 0, 0, 0);
            }
        }
        __syncthreads();
    }

    // final l reduction over l4 groups (query = l15)
    float l0 = lsum0, l1 = lsum1;
    l0 += __shfl_xor(l0, 16, 64); l0 += __shfl_xor(l0, 32, 64);
    l1 += __shfl_xor(l1, 16, 64); l1 += __shfl_xor(l1, 32, 64);
    float inv0 = 1.f / l0, inv1 = 1.f / l1;

    // O^T C-layout: (d = dt*16 + l4*4 + r, q = l15) -> packed b64 stores
    unsigned short* Wo0 = Wb + ((long)(c*768 + q0 + wave*16 + l15))*512 + h*100 + l4*4;
    unsigned short* Wo1 = Wo0 + 64*512;
    #pragma unroll
    for (int dt = 0; dt < 7; ++dt) {
        if (dt < 6 || l4 == 0) {
            *(uint2v*)(Wo0 + dt*16) = (uint2v){pk2bf(o0[dt][0]*inv0, o0[dt][1]*inv0),
                                               pk2bf(o0[dt][2]*inv0, o0[dt][3]*inv0)};
            *(uint2v*)(Wo1 + dt*16) = (uint2v){pk2bf(o1[dt][0]*inv1, o1[dt][1]*inv1),
                                               pk2bf(o1[dt][2]*inv1, o1[dt][3]*inv1)};
        }
    }
    if (h == 0) {
        unsigned short* Wz = Wb + ((long)c*768 + q0)*512 + 500;
        for (int i = tid; i < 1536; i += 256) Wz[(long)(i/12)*512 + (i%12)] = 0;
    }
}

// ---------------- MFMA W@UstT + residual + LayerNorm ----------------
__global__ void __launch_bounds__(256) k_wmln(const unsigned short* __restrict__ Wb,
                                              const unsigned short* __restrict__ UstT,
                                              const float* __restrict__ x0,
                                              const float* __restrict__ g, const float* __restrict__ b,
                                              float* __restrict__ y) {
    const int tid = threadIdx.x, wave = tid >> 6, lane = tid & 63;
    const int l15 = lane & 15, l4 = lane >> 4;
    const long r0 = (long)blockIdx.x*64 + wave*16;
    const short* Ab = (const short*)Wb + (r0 + l15)*512 + l4*8;
    const short* Bb = (const short*)UstT;
    float4v o[8];
    #pragma unroll
    for (int n = 0; n < 8; ++n) o[n] = (float4v){0.f, 0.f, 0.f, 0.f};
    for (int ks = 0; ks < 16; ++ks) {
        short8 a = *(const short8*)(Ab + ks*32);
        #pragma unroll
        for (int n = 0; n < 8; ++n) {
            short8 bb = *(const short8*)(Bb + (long)(n*16 + l15)*512 + ks*32 + l4*8);
            o[n] = __builtin_amdgcn_mfma_f32_16x16x32_bf16(a, bb, o[n], 0, 0, 0);
        }
    }
    #pragma unroll
    for (int r = 0; r < 4; ++r) {
        long row = r0 + l4*4 + r;
        float sum = 0.f;
        #pragma unroll
        for (int n = 0; n < 8; ++n) {
            int col = n*16 + l15;
            float z = 0.f;
            if (col < 100) { z = o[n][r] + x0[row*100 + col]; sum += z; }
            o[n][r] = z;
        }
        #pragma unroll
        for (int off = 1; off < 16; off <<= 1) sum += __shfl_xor(sum, off, 64);
        float mean = sum * 0.01f;
        float vs = 0.f;
        #pragma unroll
        for (int n = 0; n < 8; ++n) {
            int col = n*16 + l15;
            if (col < 100) { float d = o[n][r] - mean; vs += d*d; }
        }
        #pragma unroll
        for (int off = 1; off < 16; off <<= 1) vs += __shfl_xor(vs, off, 64);
        float inv = rsqrtf(vs * 0.01f + 1e-5f);
        #pragma unroll
        for (int n = 0; n < 8; ++n) {
            int col = n*16 + l15;
            if (col < 100) y[row*100 + col] = (o[n][r] - mean) * inv * g[col] + b[col];
        }
    }
}

// ---------------- fused FFN + residual + LN ----------------
__global__ void __launch_bounds__(256) k_ffn(const float* __restrict__ x,
        const float* __restrict__ f1w, const float* __restrict__ f1b,
        const float* __restrict__ f2w, const float* __restrict__ f2b,
        const float* __restrict__ g, const float* __restrict__ b,
        float* __restrict__ y) {
    int tid = threadIdx.x, wid = tid >> 6, lane = tid & 63;
    long base = ((long)blockIdx.x*4 + wid) * 100;
    __shared__ float xs[4][100];
    __shared__ float ts[4][64];
    bool has2 = lane < 36;
    xs[wid][lane] = x[base + lane];
    if (has2) xs[wid][64 + lane] = x[base + 64 + lane];
    __syncthreads();
    float t = f1b[lane];
    for (int k = 0; k < 100; ++k) t += xs[wid][k] * f1w[k*64 + lane];
    ts[wid][lane] = fmaxf(t, 0.f);
    __syncthreads();
    float z0 = f2b[lane];
    float z1 = has2 ? f2b[64 + lane] : 0.f;
    for (int k = 0; k < 64; ++k) {
        float tv = ts[wid][k];
        z0 += tv * f2w[k*100 + lane];
        if (has2) z1 += tv * f2w[k*100 + 64 + lane];
    }
    z0 += xs[wid][lane];
    if (has2) z1 += xs[wid][64 + lane];
    float s = z0 + z1;
    #pragma unroll
    for (int off = 1; off < 64; off <<= 1) s += __shfl_xor(s, off, 64);
    float mean = s * 0.01f;
    float d0 = z0 - mean;
    float d1 = has2 ? (z1 - mean) : 0.f;
    float vs = d0*d0 + d1*d1;
    #pragma unroll
    for (int off = 1; off < 64; off <<= 1) vs += __shfl_xor(vs, off, 64);
    float inv = rsqrtf(vs * 0.01f + 1e-5f);
    y[base + lane] = d0 * inv * g[lane] + b[lane];
    if (has2) y[base + 64 + lane] = d1 * inv * g[64 + lane] + b[64 + lane];
}

// ---------------- autoregressive predictor (composed linear map) ----------------
__global__ void __launch_bounds__(256) k_pred2(const float* __restrict__ xf,
        const float* __restrict__ Mp, const float* __restrict__ c0v,
        float* __restrict__ out) {
    int c = blockIdx.x, tid = threadIdx.x;
    __shared__ float Ml[10000];
    __shared__ float carry[100];
    for (int i = tid; i < 10000; i += 256) Ml[i] = Mp[i];
    if (tid < 100) carry[tid] = xf[((long)c*768 + 767)*100 + tid];
    __syncthreads();
    for (int s = 0; s < 10; ++s) {
        float pv = 0.f;
        if (tid < 100) {
            pv = c0v[tid];
            for (int d = 0; d < 100; ++d) pv += carry[d] * Ml[d*100 + tid];
            out[((long)c*10 + s)*100 + tid] = pv;
        }
        __syncthreads();
        if (tid < 100) carry[tid] = pv;
        __syncthreads();
    }
}

extern "C" void kernel_launch(void* const* d_in, const int* in_sizes, int n_in,
                              void* d_out, int out_size, void* d_ws, size_t ws_size,
                              hipStream_t stream) {
    const float* X    = (const float*)d_in[0];
    const float* A    = (const float*)d_in[1];
    const float* gw1  = (const float*)d_in[2];
    const float* gb1  = (const float*)d_in[3];
    const float* gw2  = (const float*)d_in[4];
    const float* gb2  = (const float*)d_in[5];
    const float* wq   = (const float*)d_in[6];
    const float* wk   = (const float*)d_in[7];
    const float* wv   = (const float*)d_in[8];
    const float* wm   = (const float*)d_in[9];
    const float* f1w  = (const float*)d_in[10];
    const float* f1b  = (const float*)d_in[11];
    const float* f2w  = (const float*)d_in[12];
    const float* f2b  = (const float*)d_in[13];
    const float* ln1g = (const float*)d_in[14];
    const float* ln1b = (const float*)d_in[15];
    const float* ln2g = (const float*)d_in[16];
    const float* ln2b = (const float*)d_in[17];
    const float* l1w  = (const float*)d_in[18];
    const float* l1b  = (const float*)d_in[19];
    const float* l2w  = (const float*)d_in[20];
    const float* l2b  = (const float*)d_in[21];
    (void)in_sizes; (void)n_in; (void)out_size; (void)ws_size;

    float* ws   = (float*)d_ws;
    float* adjh = ws + OFF_ADJ;
    float* x0   = ws + OFF_X0;
    float* x1   = ws + OFF_X1;
    float* hid  = ws + OFF_HID;
    unsigned short* xrow = (unsigned short*)(ws + OFF_XROW);
    unsigned short* xTb  = (unsigned short*)(ws + OFF_XT);
    unsigned short* Wbf  = (unsigned short*)(ws + OFF_WBF);
    unsigned short* MhT  = (unsigned short*)(ws + OFF_MHT);
    unsigned short* UstT = (unsigned short*)(ws + OFF_USTT);
    float* Mp   = ws + OFF_MP;
    float* c0v  = ws + OFF_C0;
    float* out  = (float*)d_out;

    k_adj<<<1, 1024, 0, stream>>>(A, adjh);
    k_mu2<<<497, 256, 0, stream>>>(wq, wk, wv, wm, l1w, l1b, l2w, l2b, MhT, UstT, Mp, c0v);

    // GCN
    k_spmm<<<300, 256, 0, stream>>>(adjh, X, x1, 76800);
    k_gemm<8, true, true><<<768, 256, 0, stream>>>(x1, gw1, gb1, hid, ROWS, 60, 100);
    k_spmm<<<180, 256, 0, stream>>>(adjh, hid, x1, 46080);
    k_gemm<13, false, true><<<768, 256, 0, stream>>>(x1, gw2, gb2, x0, ROWS, 100, 60);

    // encoder layers
    for (int l = 0; l < 3; ++l) {
        k_prep<<<dim3(12,32), 256, 0, stream>>>(x0, xrow, xTb);
        k_attn6<<<dim3(6,5,32), 256, 0, stream>>>(xrow, xTb, MhT + (long)l*81920, Wbf);
        k_wmln<<<384, 256, 0, stream>>>(Wbf, UstT + (long)l*65536, x0,
                                        ln1g + l*100, ln1b + l*100, x1);
        k_ffn<<<6144, 256, 0, stream>>>(x1, f1w + l*6400, f1b + l*64, f2w + l*6400, f2b + l*100,
                                        ln2g + l*100, ln2b + l*100, x0);
    }

    k_pred2<<<32, 256, 0, stream>>>(x0, Mp, c0v, out);
}

// Round 10
// 592.464 us; speedup vs baseline: 1.8197x; 1.2954x over previous
//
#include <hip/hip_runtime.h>

// GTA model: GCN(2-hop) -> 3x transformer encoder -> 10-step AR predictor.
// R9 = R8 with the k_tail xT-emit indexing fixed (xT is [c][128][768] blocked,
// not flat [128][24576]). Tail fused into one MFMA kernel per layer
// (W@Ust + res + LN1 + FFN + res + LN2 + bf16 re-emit), transposed domain.
// Attention unchanged from R7 (DMA-staged swizzled LDS, 89 us/layer).

#define ROWS 24576   // C*T = 32*768

// workspace offsets (floats)
#define OFF_ADJ   0L
#define OFF_X0    1024L
#define OFF_X1    (OFF_X0 + 2457600L)
#define OFF_HID   (OFF_X1 + 2457600L)
#define OFF_XROW  (OFF_HID + 1474560L)       // 24576*128 bf16 = 1572864 floats
#define OFF_XT    (OFF_XROW + 1572864L)
#define OFF_WBF   (OFF_XT + 1572864L)        // 24576*512 bf16 = 6291456 floats
#define OFF_MHT   (OFF_WBF + 6291456L)       // 15*128*128 bf16 = 122880 floats
#define OFF_USTT  (OFF_MHT + 122880L)        // 3*128*512 bf16 = 98304 floats
#define OFF_MP    (OFF_USTT + 98304L)        // 100*100 fp32
#define OFF_C0    (OFF_MP + 10000L)          // 100 fp32 (pad to 128)
#define OFF_F1WT  (OFF_C0 + 128L)            // 3*64*128 bf16 = 12288 floats
#define OFF_F2WT  (OFF_F1WT + 12288L)        // 3*112*64 bf16 = 10752 floats

typedef __attribute__((ext_vector_type(8))) short short8;
typedef __attribute__((ext_vector_type(4))) float float4v;
typedef __attribute__((ext_vector_type(2))) unsigned int uint2v;

__device__ inline unsigned short f2bf(float f) {
    unsigned u = __builtin_bit_cast(unsigned, f);
    return (unsigned short)((u + 0x7fffu + ((u >> 16) & 1u)) >> 16);
}
__device__ inline unsigned pk2bf(float lo, float hi) {
    return (unsigned)f2bf(lo) | ((unsigned)f2bf(hi) << 16);
}
// async global->LDS DMA, 16B per lane; LDS dest = wave-uniform base + lane*16
__device__ inline void gload16(const short* g, short* l) {
    __builtin_amdgcn_global_load_lds((const __attribute__((address_space(1))) void*)g,
                                     (__attribute__((address_space(3))) void*)l, 16, 0, 0);
}

// ---------------- adjacency normalization ----------------
__global__ void __launch_bounds__(1024) k_adj(const float* __restrict__ A, float* __restrict__ adjh) {
    __shared__ float adj[32][32];
    __shared__ float rs[32];
    int tid = threadIdx.x;
    int i = tid >> 5, j = tid & 31;
    float v = A[i*32 + j] + (i == j ? 1.f : 0.f);
    adj[i][j] = v;
    __syncthreads();
    if (tid < 32) {
        float s = 0.f;
        #pragma unroll
        for (int jj = 0; jj < 32; ++jj) s += adj[tid][jj];
        rs[tid] = s;
    }
    __syncthreads();
    adjh[i*32 + j] = adj[i][j] / rs[i];
}

// ---------------- precompute (parallel): MhT, UstT, f1wT, f2wT (bf16 padded), Mpred, c0 ----
__global__ void __launch_bounds__(256) k_mu2(const float* __restrict__ wq, const float* __restrict__ wk,
                                             const float* __restrict__ wv, const float* __restrict__ wm,
                                             const float* __restrict__ l1w, const float* __restrict__ l1b,
                                             const float* __restrict__ l2w, const float* __restrict__ l2b,
                                             const float* __restrict__ f1w, const float* __restrict__ f2w,
                                             unsigned short* __restrict__ MhT, unsigned short* __restrict__ UstT,
                                             float* __restrict__ Mp, float* __restrict__ c0v,
                                             unsigned short* __restrict__ f1wT, unsigned short* __restrict__ f2wT) {
    int bi = blockIdx.x, tid = threadIdx.x;
    if (bi < 480) {
        int mat = bi >> 4, sub = bi & 15;
        int mode = mat / 15, idx = mat % 15, l = idx / 5, h = idx % 5;
        const float* Asrc = (mode == 0 ? wq : wv) + (l*5 + h)*10000;
        const float* Bsrc = (mode == 0) ? (wk + (l*5 + h)*10000) : (wm + l*50000 + h*10000);
        int oend = sub*625 + 625;
        for (int o = sub*625 + tid; o < oend; o += 256) {
            int r = o / 100, cix = o - (o/100)*100;
            const float* arow = Asrc + r*100;
            float acc = 0.f;
            if (mode == 0) {
                const float* brow = Bsrc + cix*100;
                for (int e = 0; e < 100; ++e) acc += arow[e] * brow[e];
                MhT[(long)(l*5 + h)*16384 + cix*128 + r] = f2bf(acc * 0.1f);
            } else {
                for (int e = 0; e < 100; ++e) acc += arow[e] * Bsrc[e*100 + cix];
                UstT[(long)l*65536 + (long)cix*512 + h*100 + r] = f2bf(acc);
            }
        }
        if (sub == 0) {   // zero padding
            if (mode == 0) {
                unsigned short* M0 = MhT + (long)(l*5 + h)*16384;
                for (int i = tid; i < 28*128; i += 256) M0[(100 + i/128)*128 + (i%128)] = 0;
                for (int i = tid; i < 100*28; i += 256) M0[(i/28)*128 + 100 + (i%28)] = 0;
            } else if (h == 4) {
                unsigned short* U0 = UstT + (long)l*65536;
                for (int i = tid; i < 28*512; i += 256) U0[(long)(100 + i/512)*512 + (i%512)] = 0;
                for (int i = tid; i < 100*12; i += 256) U0[(long)(i/12)*512 + 500 + (i%12)] = 0;
            }
        }
    } else if (bi < 496) {
        int sub = bi - 480;
        int oend = sub*625 + 625;
        for (int o = sub*625 + tid; o < oend; o += 256) {
            int r = o / 100, cix = o - (o/100)*100;
            const float* arow = l1w + r*200;
            float acc = 0.f;
            for (int e = 0; e < 200; ++e) acc += arow[e] * l2w[e*100 + cix];
            Mp[r*100 + cix] = acc;
        }
    } else if (bi == 496) {
        if (tid < 100) {
            float acc = l2b[tid];
            for (int e = 0; e < 200; ++e) acc += l1b[e] * l2w[e*100 + tid];
            c0v[tid] = acc;
        }
    } else {
        int l = bi - 497;   // per-layer FFN weight transposes
        unsigned short* F1 = f1wT + (long)l*8192;
        for (int i = tid; i < 8192; i += 256) {
            int o = i >> 7, k = i & 127;
            F1[i] = (k < 100) ? f2bf(f1w[l*6400 + k*64 + o]) : (unsigned short)0;
        }
        unsigned short* F2 = f2wT + (long)l*7168;
        for (int i = tid; i < 7168; i += 256) {
            int o2 = i >> 6, k2 = i & 63;
            F2[i] = (o2 < 100) ? f2bf(f2w[l*6400 + k2*100 + o2]) : (unsigned short)0;
        }
    }
}

// ---------------- spmm: Y[i,f] = sum_j adjh[i,j] * Xin[j,f] ----------------
__global__ void __launch_bounds__(256) k_spmm(const float* __restrict__ adjh, const float* __restrict__ Xin,
                                              float* __restrict__ Y, int F) {
    __shared__ float adj[1024];
    int tid = threadIdx.x;
    for (int i = tid; i < 1024; i += 256) adj[i] = adjh[i];
    __syncthreads();
    long f = (long)blockIdx.x * 256 + tid;
    float acc[32];
    #pragma unroll
    for (int i = 0; i < 32; ++i) acc[i] = 0.f;
    for (int jj = 0; jj < 32; ++jj) {
        float xv = Xin[jj*(long)F + f];
        #pragma unroll
        for (int i = 0; i < 32; ++i) acc[i] += adj[i*32 + jj] * xv;
    }
    #pragma unroll
    for (int i = 0; i < 32; ++i) Y[i*(long)F + f] = acc[i];
}

// ---------------- fp32 tiled GEMM (GCN only) ----------------
template<int NCOLS, bool RELU, bool BIAS>
__global__ void __launch_bounds__(256) k_gemm(const float* __restrict__ A, const float* __restrict__ B,
                                              const float* __restrict__ bias, float* __restrict__ Cc,
                                              int M, int N, int K) {
    constexpr int NP = 8*NCOLS;
    int tid = threadIdx.x;
    int m0 = blockIdx.x * 32;
    int mloc = tid & 31, grp = tid >> 5;
    int n0 = grp * NCOLS;
    __shared__ float As[32][33];
    __shared__ float Bs[32][NP + 1];
    float acc[NCOLS];
    #pragma unroll
    for (int i2 = 0; i2 < NCOLS; ++i2) acc[i2] = 0.f;
    for (int k0 = 0; k0 < K; k0 += 32) {
        #pragma unroll
        for (int st = 0; st < 4; ++st) {
            int rr = (tid >> 5) + st*8, kk = tid & 31, gk = k0 + kk;
            As[rr][kk] = (gk < K) ? A[(long)(m0 + rr)*K + gk] : 0.f;
        }
        for (int i2 = tid; i2 < 32*NP; i2 += 256) {
            int kk = i2 / NP, nn = i2 - kk*NP;
            int gk = k0 + kk;
            Bs[kk][nn] = (gk < K && nn < N) ? B[(long)gk*N + nn] : 0.f;
        }
        __syncthreads();
        #pragma unroll 8
        for (int kk = 0; kk < 32; ++kk) {
            float a = As[mloc][kk];
            #pragma unroll
            for (int j2 = 0; j2 < NCOLS; ++j2) acc[j2] += a * Bs[kk][n0 + j2];
        }
        __syncthreads();
    }
    #pragma unroll
    for (int j2 = 0; j2 < NCOLS; ++j2) {
        int nn = n0 + j2;
        if (nn < N) {
            float v = acc[j2];
            if (BIAS) v += bias[nn];
            if (RELU) v = fmaxf(v, 0.f);
            Cc[(long)(m0 + mloc)*N + nn] = v;
        }
    }
}

// ---------------- x fp32 -> bf16 row-major [c][t][128] and transposed [c][128][t] ----------------
__global__ void __launch_bounds__(256) k_prep(const float* __restrict__ x, unsigned short* __restrict__ xrow,
                                              unsigned short* __restrict__ xT) {
    int c = blockIdx.y, t0 = blockIdx.x * 64;
    int tid = threadIdx.x;
    __shared__ float xs[64][101];
    const float* xp = x + ((long)c*768 + t0) * 100;
    for (int i = tid; i < 6400; i += 256) {
        int r = i / 100, d = i - r*100;
        xs[r][d] = xp[i];
    }
    __syncthreads();
    unsigned short* xro = xrow + ((long)c*768 + t0) * 128;
    for (int i = tid; i < 8192; i += 256) {
        int r = i >> 7, d = i & 127;
        xro[i] = (d < 100) ? f2bf(xs[r][d]) : (unsigned short)0;
    }
    unsigned short* xto = xT + (long)c*128*768 + t0;
    for (int i = tid; i < 8192; i += 256) {
        int d = i >> 6, t = i & 63;
        xto[(long)d*768 + t] = (d < 100) ? f2bf(xs[t][d]) : (unsigned short)0;
    }
}

// ---------------- fused Q-proj + flash attention, DMA-staged swizzled LDS (R7) ----------------
#define QP_STRIDE 136
#define PT_STRIDE 72

__global__ void __launch_bounds__(256) k_attn6(const unsigned short* __restrict__ xrow,
                                               const unsigned short* __restrict__ xT,
                                               const unsigned short* __restrict__ MhT,
                                               unsigned short* __restrict__ Wb) {
    __shared__ __align__(16) short xr[64 * 128];
    __shared__ __align__(16) short xt[112 * 64];
    __shared__ __align__(16) short scratch[4][2304];
    const int tid = threadIdx.x;
    const int wave = tid >> 6, lane = tid & 63;
    const int l15 = lane & 15, l4 = lane >> 4;
    const int c = blockIdx.z, h = blockIdx.y, q0 = blockIdx.x * 128;
    short* myq = scratch[wave];
    short* pt0 = scratch[wave];
    short* pt1 = scratch[wave] + 1152;

    short8 qb0[4], qb1[4];
    {
        const short* xq = (const short*)xrow + ((long)c*768 + q0 + wave*16 + l15)*128 + l4*8;
        short8 bq0[4], bq1[4];
        #pragma unroll
        for (int kk = 0; kk < 4; ++kk) {
            bq0[kk] = *(const short8*)(xq + kk*32);
            bq1[kk] = *(const short8*)(xq + 64*128 + kk*32);
        }
        const short* Mb = (const short*)MhT + (long)h*16384 + l15*128 + l4*8;
        float4v qc0[8], qc1[8];
        #pragma unroll
        for (int mt = 0; mt < 8; ++mt) { qc0[mt] = (float4v){0,0,0,0}; qc1[mt] = (float4v){0,0,0,0}; }
        #pragma unroll
        for (int mt = 0; mt < 8; ++mt) {
            #pragma unroll
            for (int kk = 0; kk < 4; ++kk) {
                short8 a = *(const short8*)(Mb + (mt*16)*128 + kk*32);
                qc0[mt] = __builtin_amdgcn_mfma_f32_16x16x32_bf16(a, bq0[kk], qc0[mt], 0, 0, 0);
                qc1[mt] = __builtin_amdgcn_mfma_f32_16x16x32_bf16(a, bq1[kk], qc1[mt], 0, 0, 0);
            }
        }
        #pragma unroll
        for (int mt = 0; mt < 8; ++mt)
            *(uint2v*)(myq + l15*QP_STRIDE + mt*16 + l4*4) =
                (uint2v){pk2bf(qc0[mt][0], qc0[mt][1]), pk2bf(qc0[mt][2], qc0[mt][3])};
        #pragma unroll
        for (int kk = 0; kk < 4; ++kk) qb0[kk] = *(const short8*)(myq + l15*QP_STRIDE + kk*32 + l4*8);
        #pragma unroll
        for (int mt = 0; mt < 8; ++mt)
            *(uint2v*)(myq + l15*QP_STRIDE + mt*16 + l4*4) =
                (uint2v){pk2bf(qc1[mt][0], qc1[mt][1]), pk2bf(qc1[mt][2], qc1[mt][3])};
        #pragma unroll
        for (int kk = 0; kk < 4; ++kk) qb1[kk] = *(const short8*)(myq + l15*QP_STRIDE + kk*32 + l4*8);
    }

    float4v o0[7], o1[7];
    #pragma unroll
    for (int n = 0; n < 7; ++n) { o0[n] = (float4v){0,0,0,0}; o1[n] = (float4v){0,0,0,0}; }
    float lsum0 = 0.f, lsum1 = 0.f;

    const short* xrg = (const short*)xrow + (long)c*768*128;
    const short* xtg = (const short*)xT + (long)c*128*768;
    const int rl4 = lane >> 4, cp16 = lane & 15;
    const int rl8 = lane >> 3, cp8 = lane & 7;
    const int njt = (wave == 3) ? 2 : 4;

    for (int kt = 0; kt < 12; ++kt) {
        const int key0 = kt * 64;
        #pragma unroll
        for (int j = 0; j < 4; ++j) {
            int row = wave*16 + j*4 + rl4;
            int lc = cp16 ^ (row & 7);
            gload16(xrg + (long)(key0 + row)*128 + lc*8, xr + (wave*16 + j*4)*128);
        }
        for (int j = 0; j < njt; ++j) {
            int row = wave*32 + j*8 + rl8;
            int lc = cp8 ^ (row & 7);
            gload16(xtg + (long)row*768 + key0 + lc*8, xt + (wave*32 + j*8)*64);
        }
        __syncthreads();

        float4v s0[4], s1[4];
        #pragma unroll
        for (int kn = 0; kn < 4; ++kn) { s0[kn] = (float4v){0,0,0,0}; s1[kn] = (float4v){0,0,0,0}; }
        #pragma unroll
        for (int kn = 0; kn < 4; ++kn) {
            #pragma unroll
            for (int kk = 0; kk < 4; ++kk) {
                short8 a = *(const short8*)(xr + (kn*16 + l15)*128 + (((kk*4 + l4) ^ (l15 & 7))*8));
                s0[kn] = __builtin_amdgcn_mfma_f32_16x16x32_bf16(a, qb0[kk], s0[kn], 0, 0, 0);
                s1[kn] = __builtin_amdgcn_mfma_f32_16x16x32_bf16(a, qb1[kk], s1[kn], 0, 0, 0);
            }
        }

        #pragma unroll
        for (int kn = 0; kn < 4; ++kn) {
            float p0[4], p1[4];
            #pragma unroll
            for (int r = 0; r < 4; ++r) {
                p0[r] = __expf(s0[kn][r]); lsum0 += p0[r];
                p1[r] = __expf(s1[kn][r]); lsum1 += p1[r];
            }
            *(uint2v*)(pt0 + l15*PT_STRIDE + kn*16 + l4*4) =
                (uint2v){pk2bf(p0[0], p0[1]), pk2bf(p0[2], p0[3])};
            *(uint2v*)(pt1 + l15*PT_STRIDE + kn*16 + l4*4) =
                (uint2v){pk2bf(p1[0], p1[1]), pk2bf(p1[2], p1[3])};
        }

        #pragma unroll
        for (int kk2 = 0; kk2 < 2; ++kk2) {
            short8 b0 = *(const short8*)(pt0 + l15*PT_STRIDE + kk2*32 + l4*8);
            short8 b1 = *(const short8*)(pt1 + l15*PT_STRIDE + kk2*32 + l4*8);
            #pragma unroll
            for (int dt = 0; dt < 7; ++dt) {
                short8 a = *(const short8*)(xt + (dt*16 + l15)*64 + (((kk2*4 + l4) ^ (l15 & 7))*8));
                o0[dt] = __builtin_amdgcn_mfma_f32_16x16x32_bf16(a, b0, o0[dt], 0, 0, 0);
                o1[dt] = __builtin_amdgcn_mfma_f32_16x16x32_bf16(a, b1, o1[dt], 0, 0, 0);
            }
        }
        __syncthreads();
    }

    float l0 = lsum0, l1 = lsum1;
    l0 += __shfl_xor(l0, 16, 64); l0 += __shfl_xor(l0, 32, 64);
    l1 += __shfl_xor(l1, 16, 64); l1 += __shfl_xor(l1, 32, 64);
    float inv0 = 1.f / l0, inv1 = 1.f / l1;

    unsigned short* Wo0 = Wb + ((long)(c*768 + q0 + wave*16 + l15))*512 + h*100 + l4*4;
    unsigned short* Wo1 = Wo0 + 64*512;
    #pragma unroll
    for (int dt = 0; dt < 7; ++dt) {
        if (dt < 6 || l4 == 0) {
            *(uint2v*)(Wo0 + dt*16) = (uint2v){pk2bf(o0[dt][0]*inv0, o0[dt][1]*inv0),
                                               pk2bf(o0[dt][2]*inv0, o0[dt][3]*inv0)};
            *(uint2v*)(Wo1 + dt*16) = (uint2v){pk2bf(o1[dt][0]*inv1, o1[dt][1]*inv1),
                                               pk2bf(o1[dt][2]*inv1, o1[dt][3]*inv1)};
        }
    }
    if (h == 0) {
        unsigned short* Wz = Wb + ((long)c*768 + q0)*512 + 500;
        for (int i = tid; i < 1536; i += 256) Wz[(long)(i/12)*512 + (i%12)] = 0;
    }
}

// ---------------- fused encoder tail: W@Ust + res + LN1 + FFN + res + LN2 (+ bf16 emit) ----
// grid 384 (64 rows/block, 16 rows/wave). Transposed domain: D[m=feature][n=row],
// lane holds row=l15, features l4*4+r (+16*mt) -> all transposes are same-lane packs.
// xT emit uses blocked layout [c][128][768]; 64 | 768 so each block has one c.
template<bool EMIT>
__global__ void __launch_bounds__(256) k_tail(const unsigned short* __restrict__ Wb,
        const unsigned short* __restrict__ UstT,
        const unsigned short* __restrict__ f1wT, const unsigned short* __restrict__ f2wT,
        const float* __restrict__ f1b, const float* __restrict__ f2b,
        const float* __restrict__ g1, const float* __restrict__ b1,
        const float* __restrict__ g2, const float* __restrict__ b2,
        float* __restrict__ x, unsigned short* __restrict__ xrow, unsigned short* __restrict__ xT) {
    __shared__ __align__(16) short zS[4][16*136];   // 17408 B (wave-private)
    __shared__ __align__(16) short tS[4][16*72];    // 9216 B (wave-private)
    const int tid = threadIdx.x, wave = tid >> 6, lane = tid & 63;
    const int l15 = lane & 15, l4 = lane >> 4;
    const long row = (long)blockIdx.x*64 + wave*16 + l15;
    const int cc = blockIdx.x / 12;                       // chart for this block
    const int tt = (blockIdx.x % 12)*64 + wave*16 + l15;  // t within chart
    short* myz = zS[wave];
    short* myt = tS[wave];

    // phase 1: o^T = Ust(A) . W^T(B)  -> D[m=feature][n=row]
    const short* Wr = (const short*)Wb + row*512 + l4*8;
    float4v o[8];
    #pragma unroll
    for (int mt = 0; mt < 8; ++mt) o[mt] = (float4v){0,0,0,0};
    for (int ks = 0; ks < 16; ++ks) {
        short8 b = *(const short8*)(Wr + ks*32);
        #pragma unroll
        for (int mt = 0; mt < 8; ++mt) {
            short8 a = *(const short8*)((const short*)UstT + (long)(mt*16 + l15)*512 + ks*32 + l4*8);
            o[mt] = __builtin_amdgcn_mfma_f32_16x16x32_bf16(a, b, o[mt], 0, 0, 0);
        }
    }

    // residual + LN1 (features in register index; reduce across 4 l4-lanes)
    float zv[7][4];
    float sum = 0.f;
    #pragma unroll
    for (int mt = 0; mt < 7; ++mt) {
        int f0 = mt*16 + l4*4;
        float4 xv = {0,0,0,0};
        if (f0 < 100) xv = *(const float4*)(x + row*100 + f0);
        #pragma unroll
        for (int r = 0; r < 4; ++r) {
            float z = 0.f;
            if (f0 < 100) { z = o[mt][r] + ((const float*)&xv)[r]; sum += z; }
            zv[mt][r] = z;
        }
    }
    sum += __shfl_xor(sum, 16, 64); sum += __shfl_xor(sum, 32, 64);
    float mean = sum * 0.01f;
    float vs = 0.f;
    #pragma unroll
    for (int mt = 0; mt < 7; ++mt) {
        if (mt*16 + l4*4 < 100) {
            #pragma unroll
            for (int r = 0; r < 4; ++r) { float d = zv[mt][r] - mean; vs += d*d; }
        }
    }
    vs += __shfl_xor(vs, 16, 64); vs += __shfl_xor(vs, 32, 64);
    float inv = rsqrtf(vs * 0.01f + 1e-5f);
    float x1r[7][4];
    #pragma unroll
    for (int mt = 0; mt < 7; ++mt) {
        int f0 = mt*16 + l4*4;
        float4 gv = {0,0,0,0}, bv = {0,0,0,0};
        if (f0 < 100) { gv = *(const float4*)(g1 + f0); bv = *(const float4*)(b1 + f0); }
        #pragma unroll
        for (int r = 0; r < 4; ++r)
            x1r[mt][r] = (f0 < 100) ? (zv[mt][r] - mean) * inv * ((const float*)&gv)[r] + ((const float*)&bv)[r] : 0.f;
    }

    // x1 -> wave-private LDS row-major [row l15][feature 128] (b64 packs)
    #pragma unroll
    for (int mt = 0; mt < 8; ++mt) {
        float v0 = (mt < 7) ? x1r[mt][0] : 0.f, v1 = (mt < 7) ? x1r[mt][1] : 0.f;
        float v2 = (mt < 7) ? x1r[mt][2] : 0.f, v3 = (mt < 7) ? x1r[mt][3] : 0.f;
        *(uint2v*)(myz + l15*136 + mt*16 + l4*4) = (uint2v){pk2bf(v0, v1), pk2bf(v2, v3)};
    }

    // FFN1: t^T = f1wT(A) . x1^T(B), relu, -> tS
    float4v t2[4];
    #pragma unroll
    for (int m2t = 0; m2t < 4; ++m2t) t2[m2t] = (float4v){0,0,0,0};
    #pragma unroll
    for (int ks = 0; ks < 4; ++ks) {
        short8 b = *(const short8*)(myz + l15*136 + ks*32 + l4*8);
        #pragma unroll
        for (int m2t = 0; m2t < 4; ++m2t) {
            short8 a = *(const short8*)((const short*)f1wT + (m2t*16 + l15)*128 + ks*32 + l4*8);
            t2[m2t] = __builtin_amdgcn_mfma_f32_16x16x32_bf16(a, b, t2[m2t], 0, 0, 0);
        }
    }
    #pragma unroll
    for (int m2t = 0; m2t < 4; ++m2t) {
        int m20 = m2t*16 + l4*4;
        float4 bv = *(const float4*)(f1b + m20);
        float v0 = fmaxf(t2[m2t][0] + ((const float*)&bv)[0], 0.f);
        float v1 = fmaxf(t2[m2t][1] + ((const float*)&bv)[1], 0.f);
        float v2 = fmaxf(t2[m2t][2] + ((const float*)&bv)[2], 0.f);
        float v3 = fmaxf(t2[m2t][3] + ((const float*)&bv)[3], 0.f);
        *(uint2v*)(myt + l15*72 + m20) = (uint2v){pk2bf(v0, v1), pk2bf(v2, v3)};
    }

    // FFN2: y^T = f2wT(A) . t^T(B)
    float4v o3[7];
    #pragma unroll
    for (int m3t = 0; m3t < 7; ++m3t) o3[m3t] = (float4v){0,0,0,0};
    #pragma unroll
    for (int ks2 = 0; ks2 < 2; ++ks2) {
        short8 b = *(const short8*)(myt + l15*72 + ks2*32 + l4*8);
        #pragma unroll
        for (int m3t = 0; m3t < 7; ++m3t) {
            short8 a = *(const short8*)((const short*)f2wT + (m3t*16 + l15)*64 + ks2*32 + l4*8);
            o3[m3t] = __builtin_amdgcn_mfma_f32_16x16x32_bf16(a, b, o3[m3t], 0, 0, 0);
        }
    }

    // + f2b + residual(x1) + LN2
    float z2[7][4];
    float sum2 = 0.f;
    #pragma unroll
    for (int m3t = 0; m3t < 7; ++m3t) {
        int f0 = m3t*16 + l4*4;
        float4 bv = {0,0,0,0};
        if (f0 < 100) bv = *(const float4*)(f2b + f0);
        #pragma unroll
        for (int r = 0; r < 4; ++r) {
            float z = 0.f;
            if (f0 < 100) { z = o3[m3t][r] + ((const float*)&bv)[r] + x1r[m3t][r]; sum2 += z; }
            z2[m3t][r] = z;
        }
    }
    sum2 += __shfl_xor(sum2, 16, 64); sum2 += __shfl_xor(sum2, 32, 64);
    float mean2 = sum2 * 0.01f;
    float vs2 = 0.f;
    #pragma unroll
    for (int m3t = 0; m3t < 7; ++m3t) {
        if (m3t*16 + l4*4 < 100) {
            #pragma unroll
            for (int r = 0; r < 4; ++r) { float d = z2[m3t][r] - mean2; vs2 += d*d; }
        }
    }
    vs2 += __shfl_xor(vs2, 16, 64); vs2 += __shfl_xor(vs2, 32, 64);
    float inv2 = rsqrtf(vs2 * 0.01f + 1e-5f);

    // emit: x (fp32), xrow/xT (bf16, blocked xT layout) for next layer
    unsigned short* xTc = EMIT ? (xT + (long)cc*98304 + tt) : nullptr;
    #pragma unroll
    for (int m3t = 0; m3t < 7; ++m3t) {
        int f0 = m3t*16 + l4*4;
        if (f0 < 100) {
            float4 gv = *(const float4*)(g2 + f0);
            float4 bv = *(const float4*)(b2 + f0);
            float y[4];
            #pragma unroll
            for (int r = 0; r < 4; ++r)
                y[r] = (z2[m3t][r] - mean2) * inv2 * ((const float*)&gv)[r] + ((const float*)&bv)[r];
            *(float4*)(x + row*100 + f0) = (float4){y[0], y[1], y[2], y[3]};
            if (EMIT) {
                *(uint2v*)(xrow + row*128 + f0) = (uint2v){pk2bf(y[0], y[1]), pk2bf(y[2], y[3])};
                #pragma unroll
                for (int r = 0; r < 4; ++r)
                    xTc[(long)(f0 + r)*768] = f2bf(y[r]);
            }
        } else if (EMIT) {
            *(uint2v*)(xrow + row*128 + f0) = (uint2v){0u, 0u};
            #pragma unroll
            for (int r = 0; r < 4; ++r)
                if (f0 + r < 112) xTc[(long)(f0 + r)*768] = 0;
        }
    }
    if (EMIT) *(uint2v*)(xrow + row*128 + 112 + l4*4) = (uint2v){0u, 0u};
}

// ---------------- autoregressive predictor (composed linear map) ----------------
__global__ void __launch_bounds__(256) k_pred2(const float* __restrict__ xf,
        const float* __restrict__ Mp, const float* __restrict__ c0v,
        float* __restrict__ out) {
    int c = blockIdx.x, tid = threadIdx.x;
    __shared__ float Ml[10000];
    __shared__ float carry[100];
    for (int i = tid; i < 10000; i += 256) Ml[i] = Mp[i];
    if (tid < 100) carry[tid] = xf[((long)c*768 + 767)*100 + tid];
    __syncthreads();
    for (int s = 0; s < 10; ++s) {
        float pv = 0.f;
        if (tid < 100) {
            pv = c0v[tid];
            for (int d = 0; d < 100; ++d) pv += carry[d] * Ml[d*100 + tid];
            out[((long)c*10 + s)*100 + tid] = pv;
        }
        __syncthreads();
        if (tid < 100) carry[tid] = pv;
        __syncthreads();
    }
}

extern "C" void kernel_launch(void* const* d_in, const int* in_sizes, int n_in,
                              void* d_out, int out_size, void* d_ws, size_t ws_size,
                              hipStream_t stream) {
    const float* X    = (const float*)d_in[0];
    const float* A    = (const float*)d_in[1];
    const float* gw1  = (const float*)d_in[2];
    const float* gb1  = (const float*)d_in[3];
    const float* gw2  = (const float*)d_in[4];
    const float* gb2  = (const float*)d_in[5];
    const float* wq   = (const float*)d_in[6];
    const float* wk   = (const float*)d_in[7];
    const float* wv   = (const float*)d_in[8];
    const float* wm   = (const float*)d_in[9];
    const float* f1w  = (const float*)d_in[10];
    const float* f1b  = (const float*)d_in[11];
    const float* f2w  = (const float*)d_in[12];
    const float* f2b  = (const float*)d_in[13];
    const float* ln1g = (const float*)d_in[14];
    const float* ln1b = (const float*)d_in[15];
    const float* ln2g = (const float*)d_in[16];
    const float* ln2b = (const float*)d_in[17];
    const float* l1w  = (const float*)d_in[18];
    const float* l1b  = (const float*)d_in[19];
    const float* l2w  = (const float*)d_in[20];
    const float* l2b  = (const float*)d_in[21];
    (void)in_sizes; (void)n_in; (void)out_size; (void)ws_size;

    float* ws   = (float*)d_ws;
    float* adjh = ws + OFF_ADJ;
    float* x0   = ws + OFF_X0;
    float* x1   = ws + OFF_X1;
    float* hid  = ws + OFF_HID;
    unsigned short* xrow = (unsigned short*)(ws + OFF_XROW);
    unsigned short* xTb  = (unsigned short*)(ws + OFF_XT);
    unsigned short* Wbf  = (unsigned short*)(ws + OFF_WBF);
    unsigned short* MhT  = (unsigned short*)(ws + OFF_MHT);
    unsigned short* UstT = (unsigned short*)(ws + OFF_USTT);
    float* Mp   = ws + OFF_MP;
    float* c0v  = ws + OFF_C0;
    unsigned short* f1wT = (unsigned short*)(ws + OFF_F1WT);
    unsigned short* f2wT = (unsigned short*)(ws + OFF_F2WT);
    float* out  = (float*)d_out;

    k_adj<<<1, 1024, 0, stream>>>(A, adjh);
    k_mu2<<<500, 256, 0, stream>>>(wq, wk, wv, wm, l1w, l1b, l2w, l2b, f1w, f2w,
                                   MhT, UstT, Mp, c0v, f1wT, f2wT);

    // GCN
    k_spmm<<<300, 256, 0, stream>>>(adjh, X, x1, 76800);
    k_gemm<8, true, true><<<768, 256, 0, stream>>>(x1, gw1, gb1, hid, ROWS, 60, 100);
    k_spmm<<<180, 256, 0, stream>>>(adjh, hid, x1, 46080);
    k_gemm<13, false, true><<<768, 256, 0, stream>>>(x1, gw2, gb2, x0, ROWS, 100, 60);

    // encoder layers: attn + fused tail
    k_prep<<<dim3(12,32), 256, 0, stream>>>(x0, xrow, xTb);
    for (int l = 0; l < 3; ++l) {
        k_attn6<<<dim3(6,5,32), 256, 0, stream>>>(xrow, xTb, MhT + (long)l*81920, Wbf);
        if (l < 2)
            k_tail<true><<<384, 256, 0, stream>>>(Wbf, UstT + (long)l*65536,
                f1wT + (long)l*8192, f2wT + (long)l*7168, f1b + l*64, f2b + l*100,
                ln1g + l*100, ln1b + l*100, ln2g + l*100, ln2b + l*100, x0, xrow, xTb);
        else
            k_tail<false><<<384, 256, 0, stream>>>(Wbf, UstT + (long)l*65536,
                f1wT + (long)l*8192, f2wT + (long)l*7168, f1b + l*64, f2b + l*100,
                ln1g + l*100, ln1b + l*100, ln2g + l*100, ln2b + l*100, x0, xrow, xTb);
    }

    k_pred2<<<32, 256, 0, stream>>>(x0, Mp, c0v, out);
}